// Round 2
// baseline (2896.120 us; speedup 1.0000x reference)
//
#include <hip/hip_runtime.h>
#include <math.h>

#define NHEAD 8
#define DMODEL 256
#define DKV 32
#define BATCH 2
#define LSEQ 1024
#define LN_EPS 1e-5f
#define INV_SQRT_DK 0.17677669529663687f
#define TI 4

// ---------------- Kernel A: LayerNorm stats (mu, rsigma per row) ----------------
__global__ void ln_stats_kernel(const float* __restrict__ hin, float* __restrict__ stats) {
  int row = blockIdx.x;
  int t = threadIdx.x;
  float x = hin[(size_t)row * DMODEL + t];
  float s = x, ss = x * x;
#pragma unroll
  for (int off = 32; off > 0; off >>= 1) {
    s += __shfl_xor(s, off);
    ss += __shfl_xor(ss, off);
  }
  __shared__ float red[8];
  int wave = t >> 6, lane = t & 63;
  if (lane == 0) { red[wave] = s; red[4 + wave] = ss; }
  __syncthreads();
  if (t == 0) {
    float S = red[0] + red[1] + red[2] + red[3];
    float SS = red[4] + red[5] + red[6] + red[7];
    float mu = S * (1.0f / DMODEL);
    float var = SS * (1.0f / DMODEL) - mu * mu;
    stats[row * 2] = mu;
    stats[row * 2 + 1] = rsqrtf(var + LN_EPS);
  }
}

// ---------------- Kernel B: QKV projection GEMM with fused LayerNorm ----------------
// C[2048 x 768] = LN(h)[2048 x 256] @ W^T ; 128x64 tile, 8x4 micro-tile
#define GBM 128
#define GBN 64
__global__ __launch_bounds__(256) void qkv_gemm_kernel(
    const float* __restrict__ hin, const float* __restrict__ stats,
    const float* __restrict__ ln_g, const float* __restrict__ ln_b,
    const float* __restrict__ w_qs, const float* __restrict__ w_ks,
    const float* __restrict__ w_vs, float* __restrict__ q_ws,
    float* __restrict__ k_ws, float* __restrict__ v_ws) {
  __shared__ float As[16][GBM + 4];
  __shared__ float Bs[16][GBN + 4];
  int m0 = blockIdx.x * GBM;
  int nb = blockIdx.y;             // 0..11
  int mat = nb >> 2;               // 0:q 1:k 2:v
  int n0 = (nb & 3) * GBN;
  const float* W = (mat == 0) ? w_qs : (mat == 1 ? w_ks : w_vs);
  float* O = (mat == 0) ? q_ws : (mat == 1 ? k_ws : v_ws);
  int t = threadIdx.x;
  int r = t >> 2, c4 = (t & 3) * 4;
  float mu0 = stats[(m0 + r) * 2], rs0 = stats[(m0 + r) * 2 + 1];
  float mu1 = stats[(m0 + 64 + r) * 2], rs1 = stats[(m0 + 64 + r) * 2 + 1];
  int tx = t & 15, ty = t >> 4;
  float acc[8][4] = {};
  for (int k0 = 0; k0 < DMODEL; k0 += 16) {
    __syncthreads();
    float4 g = *(const float4*)&ln_g[k0 + c4];
    float4 be = *(const float4*)&ln_b[k0 + c4];
    float4 a0 = *(const float4*)&hin[(size_t)(m0 + r) * DMODEL + k0 + c4];
    float4 a1 = *(const float4*)&hin[(size_t)(m0 + 64 + r) * DMODEL + k0 + c4];
    As[c4 + 0][r] = (a0.x - mu0) * rs0 * g.x + be.x;
    As[c4 + 1][r] = (a0.y - mu0) * rs0 * g.y + be.y;
    As[c4 + 2][r] = (a0.z - mu0) * rs0 * g.z + be.z;
    As[c4 + 3][r] = (a0.w - mu0) * rs0 * g.w + be.w;
    As[c4 + 0][64 + r] = (a1.x - mu1) * rs1 * g.x + be.x;
    As[c4 + 1][64 + r] = (a1.y - mu1) * rs1 * g.y + be.y;
    As[c4 + 2][64 + r] = (a1.z - mu1) * rs1 * g.z + be.z;
    As[c4 + 3][64 + r] = (a1.w - mu1) * rs1 * g.w + be.w;
    float4 wv = *(const float4*)&W[(size_t)(n0 + r) * DMODEL + k0 + c4];
    Bs[c4 + 0][r] = wv.x;
    Bs[c4 + 1][r] = wv.y;
    Bs[c4 + 2][r] = wv.z;
    Bs[c4 + 3][r] = wv.w;
    __syncthreads();
#pragma unroll
    for (int kk = 0; kk < 16; kk++) {
      float4 av0 = *(const float4*)&As[kk][ty * 8];
      float4 av1 = *(const float4*)&As[kk][ty * 8 + 4];
      float4 bv = *(const float4*)&Bs[kk][tx * 4];
      float am[8] = {av0.x, av0.y, av0.z, av0.w, av1.x, av1.y, av1.z, av1.w};
      float bm[4] = {bv.x, bv.y, bv.z, bv.w};
#pragma unroll
      for (int ii = 0; ii < 8; ii++)
#pragma unroll
        for (int jj = 0; jj < 4; jj++) acc[ii][jj] += am[ii] * bm[jj];
    }
  }
#pragma unroll
  for (int ii = 0; ii < 8; ii++) {
    float4 st = {acc[ii][0], acc[ii][1], acc[ii][2], acc[ii][3]};
    *(float4*)&O[(size_t)(m0 + ty * 8 + ii) * DMODEL + n0 + tx * 4] = st;
  }
}

// ---------------- Kernel C: fused attention, block = (b, 4 consecutive i) ----------------
// 512 threads = 8 waves; wave w owns j in [w*128,(w+1)*128). Lane l: h=l>>3, dg=l&7 (d=dg*4..+3).
// k/v rows loaded as wave-coalesced 1KB float4 loads; dot reduced over the 8 dg-lanes by shfl_xor.
__global__ __launch_bounds__(512, 4) void attn_kernel(
    const float* __restrict__ q_ws, const float* __restrict__ k_ws,
    const float* __restrict__ v_ws, const float* __restrict__ bias,
    const float* __restrict__ hin, const float* __restrict__ fc_w,
    const float* __restrict__ fc_b, float* __restrict__ out,
    float* __restrict__ attn_out) {
  __shared__ float pw[8 * 8 * TI * 16];      // per-wave p transpose: [w][h][i][16]
  __shared__ float lred[8 * 8 * TI];         // [w][h][i]
  __shared__ float linv[NHEAD * TI];         // [h][i]
  __shared__ float4 accred[NHEAD * 8 * TI * 8];  // [(h*8+dg)*TI+i][w]
  __shared__ float embv[TI * 256];           // [i][d_model_flat]

  int blk = blockIdx.x;
  int b = blk >> 8;
  int i0 = (blk & 255) * TI;
  int t = threadIdx.x;
  int w = t >> 6, l = t & 63;
  int h = l >> 3, dg = l & 7;

  const float* kbase = k_ws + ((size_t)b * LSEQ) * DMODEL + l * 4;
  const float* vbase = v_ws + ((size_t)b * LSEQ) * DMODEL + l * 4;
  const float* bbase = bias + ((size_t)(b * LSEQ + i0)) * LSEQ * DKV + dg * 4;

  float4 q4[TI];
#pragma unroll
  for (int i = 0; i < TI; i++)
    q4[i] = *(const float4*)(q_ws + ((size_t)(b * LSEQ + i0 + i)) * DMODEL + l * 4);

  float4 acc4[TI];
  float lsum[TI];
#pragma unroll
  for (int i = 0; i < TI; i++) {
    acc4[i] = make_float4(0.f, 0.f, 0.f, 0.f);
    lsum[i] = 0.f;
  }

  int jbase = w * 128;
  for (int jc = 0; jc < 8; ++jc) {
#pragma unroll
    for (int j16 = 0; j16 < 16; ++j16) {
      int j = jbase + jc * 16 + j16;
      float4 kv = *(const float4*)(kbase + (size_t)j * DMODEL);
      float4 vv = *(const float4*)(vbase + (size_t)j * DMODEL);
      float4 bb[TI];
#pragma unroll
      for (int i = 0; i < TI; i++)
        bb[i] = *(const float4*)(bbase + ((size_t)i * LSEQ + j) * DKV);
#pragma unroll
      for (int i = 0; i < TI; i++) {
        float s = (kv.x + bb[i].x) * q4[i].x + (kv.y + bb[i].y) * q4[i].y +
                  (kv.z + bb[i].z) * q4[i].z + (kv.w + bb[i].w) * q4[i].w;
        s += __shfl_xor(s, 1);
        s += __shfl_xor(s, 2);
        s += __shfl_xor(s, 4);
        float p = __expf(s * INV_SQRT_DK);
        lsum[i] += p;
        acc4[i].x += p * (vv.x + bb[i].x);
        acc4[i].y += p * (vv.y + bb[i].y);
        acc4[i].z += p * (vv.z + bb[i].z);
        acc4[i].w += p * (vv.w + bb[i].w);
        if (dg == 0) pw[(w * 32 + h * TI + i) * 16 + j16] = p;
      }
    }
    // write unnormalized p chunk to global (wave-private LDS -> coalesced 64B segments)
#pragma unroll
    for (int it = 0; it < 2; it++) {
      int f = it * 256 + l * 4;
      int hh = f >> 6, ii = (f >> 4) & 3, jj = f & 15;
      float4 pv = *(const float4*)&pw[w * 512 + f];
      *(float4*)&attn_out[(((size_t)(hh * BATCH + b)) * LSEQ + i0 + ii) * LSEQ + jbase +
                          jc * 16 + jj] = pv;
    }
  }

  // softmax denominators: per-wave partials -> block reduce
  if (dg == 0) {
#pragma unroll
    for (int i = 0; i < TI; i++) lred[(w * NHEAD + h) * TI + i] = lsum[i];
  }
  __syncthreads();
  if (t < NHEAD * TI) {
    float s = 0.f;
#pragma unroll
    for (int w8 = 0; w8 < 8; w8++) s += lred[w8 * NHEAD * TI + t];
    linv[t] = 1.0f / s;
  }
  __syncthreads();

  // rescale pass over this wave's own attn region (L2-hot): 512B contiguous chunks
#pragma unroll
  for (int it = 0; it < 16; it++) {
    int f = it * 256 + l * 4;  // 0..4095 over [8h][4i][128j]
    int hh = f >> 9, ii = (f >> 7) & 3, jj = f & 127;
    float sc = linv[hh * TI + ii];
    size_t a = (((size_t)(hh * BATCH + b)) * LSEQ + i0 + ii) * LSEQ + jbase + jj;
    float4 v = *(float4*)&attn_out[a];
    v.x *= sc; v.y *= sc; v.z *= sc; v.w *= sc;
    *(float4*)&attn_out[a] = v;
  }

  // emb reduction across waves
#pragma unroll
  for (int i = 0; i < TI; i++) accred[((h * 8 + dg) * TI + i) * 8 + w] = acc4[i];
  __syncthreads();
  if (t < 256) {
    float4 s = make_float4(0.f, 0.f, 0.f, 0.f);
#pragma unroll
    for (int w8 = 0; w8 < 8; w8++) {
      float4 x = accred[t * 8 + w8];
      s.x += x.x; s.y += x.y; s.z += x.z; s.w += x.w;
    }
    int hd = t >> 2;  // h*8+dg
    int i = t & 3;
    float sc = linv[(hd >> 3) * TI + i];
    s.x *= sc; s.y *= sc; s.z *= sc; s.w *= sc;
    *(float4*)&embv[i * 256 + hd * 4] = s;
  }
  __syncthreads();

  // FC + bias + residual: wave handles 4 output channels per pass, coalesced fc_w reads
  int kk = l & 15;
  int cg = l >> 4;
#pragma unroll
  for (int pass = 0; pass < 8; pass++) {
    int ch = pass * 32 + w * 4 + cg;
    float4 wv[4];
#pragma unroll
    for (int cc = 0; cc < 4; cc++)
      wv[cc] = *(const float4*)(fc_w + (size_t)ch * DMODEL + (cc * 16 + kk) * 4);
    float po[TI];
#pragma unroll
    for (int i = 0; i < TI; i++) {
      float s = 0.f;
#pragma unroll
      for (int cc = 0; cc < 4; cc++) {
        float4 e = *(const float4*)&embv[i * 256 + (cc * 16 + kk) * 4];
        s += wv[cc].x * e.x + wv[cc].y * e.y + wv[cc].z * e.z + wv[cc].w * e.w;
      }
      po[i] = s;
    }
#pragma unroll
    for (int m = 1; m < 16; m <<= 1) {
#pragma unroll
      for (int i = 0; i < TI; i++) po[i] += __shfl_xor(po[i], m);
    }
    if (kk == 0) {
      float fb = fc_b[ch];
#pragma unroll
      for (int i = 0; i < TI; i++) {
        size_t rr = ((size_t)(b * LSEQ + i0 + i)) * DMODEL + ch;
        out[rr] = po[i] + fb + hin[rr];
      }
    }
  }
}

extern "C" void kernel_launch(void* const* d_in, const int* in_sizes, int n_in,
                              void* d_out, int out_size, void* d_ws, size_t ws_size,
                              hipStream_t stream) {
  const float* h = (const float*)d_in[0];
  const float* bias = (const float*)d_in[1];
  const float* w_qs = (const float*)d_in[2];
  const float* w_ks = (const float*)d_in[3];
  const float* w_vs = (const float*)d_in[4];
  const float* ln_g = (const float*)d_in[5];
  const float* ln_b = (const float*)d_in[6];
  const float* fc_w = (const float*)d_in[7];
  const float* fc_b = (const float*)d_in[8];
  float* out = (float*)d_out;
  float* attn_out = out + (size_t)BATCH * LSEQ * DMODEL;

  float* ws = (float*)d_ws;
  float* stats = ws;                                   // 4096 floats
  float* q_ws = ws + 4096;
  float* k_ws = q_ws + (size_t)BATCH * LSEQ * DMODEL;
  float* v_ws = k_ws + (size_t)BATCH * LSEQ * DMODEL;

  ln_stats_kernel<<<BATCH * LSEQ, 256, 0, stream>>>(h, stats);
  qkv_gemm_kernel<<<dim3(16, 12), 256, 0, stream>>>(h, stats, ln_g, ln_b, w_qs, w_ks,
                                                    w_vs, q_ws, k_ws, v_ws);
  attn_kernel<<<BATCH * LSEQ / TI, 512, 0, stream>>>(q_ws, k_ws, v_ws, bias, h, fc_w,
                                                     fc_b, out, attn_out);
}

// Round 3
// 1480.379 us; speedup vs baseline: 1.9563x; 1.9563x over previous
//
#include <hip/hip_runtime.h>
#include <math.h>

#define NHEAD 8
#define DMODEL 256
#define DKV 32
#define BATCH 2
#define LSEQ 1024
#define LN_EPS 1e-5f
#define INV_SQRT_DK 0.17677669529663687f
#define TI 4
#define NCHUNK 16  // 1024 / 64 j per chunk

// ---------------- Kernel A: QKV projection GEMM, LN fused, k/v stored transposed ----------------
// q_ws:  [b*1024+i][h*32+d]   (row layout, for per-head q fragment loads)
// kt/vt: [(b*8+h)*1024+j][d]  (head-major, for coalesced per-wave streams)
#define GBM 128
#define GBN 64
__global__ __launch_bounds__(256) void qkv_gemm_kernel(
    const float* __restrict__ hin, const float* __restrict__ ln_g,
    const float* __restrict__ ln_b, const float* __restrict__ w_qs,
    const float* __restrict__ w_ks, const float* __restrict__ w_vs,
    float* __restrict__ q_ws, float* __restrict__ kt_ws, float* __restrict__ vt_ws) {
  __shared__ float As[16][GBM + 4];
  __shared__ float Bs[16][GBN + 4];
  __shared__ float stats_s[GBM][2];
  int m0 = blockIdx.x * GBM;
  int nb = blockIdx.y;  // 0..11
  int mat = nb >> 2;    // 0:q 1:k 2:v
  int n0 = (nb & 3) * GBN;
  const float* W = (mat == 0) ? w_qs : (mat == 1 ? w_ks : w_vs);
  int t = threadIdx.x;

  // inline LN stats: 2 threads per row, 128 rows
  {
    int r = t >> 1, hf = t & 1;
    const float* row = hin + (size_t)(m0 + r) * DMODEL + hf * 128;
    float s = 0.f, ss = 0.f;
#pragma unroll
    for (int c = 0; c < 32; c++) {
      float4 x = *(const float4*)&row[c * 4];
      s += x.x + x.y + x.z + x.w;
      ss += x.x * x.x + x.y * x.y + x.z * x.z + x.w * x.w;
    }
    s += __shfl_xor(s, 1);
    ss += __shfl_xor(ss, 1);
    if (hf == 0) {
      float mu = s * (1.0f / DMODEL);
      float var = ss * (1.0f / DMODEL) - mu * mu;
      stats_s[r][0] = mu;
      stats_s[r][1] = rsqrtf(var + LN_EPS);
    }
  }
  __syncthreads();

  int r = t >> 2, c4 = (t & 3) * 4;
  float mu0 = stats_s[r][0], rs0 = stats_s[r][1];
  float mu1 = stats_s[64 + r][0], rs1 = stats_s[64 + r][1];
  int tx = t & 15, ty = t >> 4;
  float acc[8][4] = {};
  for (int k0 = 0; k0 < DMODEL; k0 += 16) {
    __syncthreads();
    float4 g = *(const float4*)&ln_g[k0 + c4];
    float4 be = *(const float4*)&ln_b[k0 + c4];
    float4 a0 = *(const float4*)&hin[(size_t)(m0 + r) * DMODEL + k0 + c4];
    float4 a1 = *(const float4*)&hin[(size_t)(m0 + 64 + r) * DMODEL + k0 + c4];
    As[c4 + 0][r] = (a0.x - mu0) * rs0 * g.x + be.x;
    As[c4 + 1][r] = (a0.y - mu0) * rs0 * g.y + be.y;
    As[c4 + 2][r] = (a0.z - mu0) * rs0 * g.z + be.z;
    As[c4 + 3][r] = (a0.w - mu0) * rs0 * g.w + be.w;
    As[c4 + 0][64 + r] = (a1.x - mu1) * rs1 * g.x + be.x;
    As[c4 + 1][64 + r] = (a1.y - mu1) * rs1 * g.y + be.y;
    As[c4 + 2][64 + r] = (a1.z - mu1) * rs1 * g.z + be.z;
    As[c4 + 3][64 + r] = (a1.w - mu1) * rs1 * g.w + be.w;
    float4 wv = *(const float4*)&W[(size_t)(n0 + r) * DMODEL + k0 + c4];
    Bs[c4 + 0][r] = wv.x;
    Bs[c4 + 1][r] = wv.y;
    Bs[c4 + 2][r] = wv.z;
    Bs[c4 + 3][r] = wv.w;
    __syncthreads();
#pragma unroll
    for (int kk = 0; kk < 16; kk++) {
      float4 av0 = *(const float4*)&As[kk][ty * 8];
      float4 av1 = *(const float4*)&As[kk][ty * 8 + 4];
      float4 bv = *(const float4*)&Bs[kk][tx * 4];
      float am[8] = {av0.x, av0.y, av0.z, av0.w, av1.x, av1.y, av1.z, av1.w};
      float bm[4] = {bv.x, bv.y, bv.z, bv.w};
#pragma unroll
      for (int ii = 0; ii < 8; ii++)
#pragma unroll
        for (int jj = 0; jj < 4; jj++) acc[ii][jj] += am[ii] * bm[jj];
    }
  }
  int n = n0 + tx * 4;
#pragma unroll
  for (int ii = 0; ii < 8; ii++) {
    int row = m0 + ty * 8 + ii;
    float4 st = {acc[ii][0], acc[ii][1], acc[ii][2], acc[ii][3]};
    if (mat == 0) {
      *(float4*)&q_ws[(size_t)row * DMODEL + n] = st;
    } else {
      int b = row >> 10, j = row & 1023;
      int hh = n >> 5, d = n & 31;
      float* O = (mat == 1) ? kt_ws : vt_ws;
      *(float4*)&O[(((size_t)(b * NHEAD + hh)) * LSEQ + j) * DKV + d] = st;
    }
  }
}

// ---------------- Kernel B: fused attention. Block=(b, 4 i-rows), wave=head ----------------
// 512 thr = 8 waves. Lane l: jg=l>>3 (j-group), dg=l&7 (d-fragment of 4).
// Per 64-j chunk: bias staged to LDS (shared by heads); k/v streamed coalesced per head.
__global__ __launch_bounds__(512, 4) void attn_kernel(
    const float* __restrict__ q_ws, const float* __restrict__ kt,
    const float* __restrict__ vt, const float* __restrict__ bias,
    const float* __restrict__ hin, const float* __restrict__ fc_w,
    const float* __restrict__ fc_b, float* __restrict__ out,
    float* __restrict__ attn_out, float* __restrict__ inv_ws) {
  __shared__ float bs[TI * 64 * DKV];  // 32 KB bias chunk [i][j_local][d]
  __shared__ float embv[TI * DMODEL];  // 4 KB

  int blk = blockIdx.x;
  int xcd = blk & 7;
  int b = xcd >> 2;                       // XCD-affine batch for k/v L2 locality
  int r = (blk >> 3) * 4 + (xcd & 3);     // 0..255
  int i0 = r * TI;
  int t = threadIdx.x;
  int w = t >> 6, l = t & 63;
  int jg = l >> 3, dg = l & 7;
  int h = w;

  const float* bias_base = bias + ((size_t)(b * LSEQ + i0)) * LSEQ * DKV;
  const float* kbase = kt + ((size_t)(b * NHEAD + h)) * LSEQ * DKV;
  const float* vbase = vt + ((size_t)(b * NHEAD + h)) * LSEQ * DKV;

  float4 q4[TI];
#pragma unroll
  for (int i = 0; i < TI; i++)
    q4[i] = *(const float4*)(q_ws + ((size_t)(b * LSEQ + i0 + i)) * DMODEL + h * DKV + dg * 4);

  float4 acc[TI];
  float lsum[TI];
#pragma unroll
  for (int i = 0; i < TI; i++) {
    acc[i] = make_float4(0.f, 0.f, 0.f, 0.f);
    lsum[i] = 0.f;
  }

  // prologue: stage chunk 0
  float4 pf[TI];
#pragma unroll
  for (int i = 0; i < TI; i++)
    pf[i] = *(const float4*)(bias_base + (size_t)i * (LSEQ * DKV) + t * 4);
#pragma unroll
  for (int i = 0; i < TI; i++) *(float4*)&bs[i * 2048 + t * 4] = pf[i];
  __syncthreads();

  for (int ch = 0; ch < NCHUNK; ch++) {
    if (ch + 1 < NCHUNK) {
#pragma unroll
      for (int i = 0; i < TI; i++)
        pf[i] = *(const float4*)(bias_base + (size_t)i * (LSEQ * DKV) + (ch + 1) * 2048 + t * 4);
    }
    const float* kc = kbase + (size_t)ch * 2048;
    const float* vc = vbase + (size_t)ch * 2048;
#pragma unroll
    for (int c = 0; c < 8; c++) {
      float4 kv = *(const float4*)(kc + (c * 64 + l) * 4);
      float4 vv = *(const float4*)(vc + (c * 64 + l) * 4);
#pragma unroll
      for (int i = 0; i < TI; i++) {
        float4 bb = *(const float4*)&bs[i * 2048 + c * 256 + jg * 32 + dg * 4];
        float s = (kv.x + bb.x) * q4[i].x + (kv.y + bb.y) * q4[i].y +
                  (kv.z + bb.z) * q4[i].z + (kv.w + bb.w) * q4[i].w;
        s += __shfl_xor(s, 1);
        s += __shfl_xor(s, 2);
        s += __shfl_xor(s, 4);
        float p = __expf(s * INV_SQRT_DK);
        lsum[i] += p;
        acc[i].x += p * (vv.x + bb.x);
        acc[i].y += p * (vv.y + bb.y);
        acc[i].z += p * (vv.z + bb.z);
        acc[i].w += p * (vv.w + bb.w);
        // unnormalized p -> attn_out (8 lanes active; 32B line-local, merges in L2)
        if (dg == c)
          attn_out[(((size_t)(h * BATCH + b)) * LSEQ + i0 + i) * LSEQ + ch * 64 + c * 8 + jg] = p;
      }
    }
    __syncthreads();  // all waves done reading bs
    if (ch + 1 < NCHUNK) {
#pragma unroll
      for (int i = 0; i < TI; i++) *(float4*)&bs[i * 2048 + t * 4] = pf[i];
      __syncthreads();
    }
  }

  // wave-local reductions over jg lanes
  float inv_l[TI];
#pragma unroll
  for (int i = 0; i < TI; i++) {
#pragma unroll
    for (int m = 8; m < 64; m <<= 1) {
      lsum[i] += __shfl_xor(lsum[i], m);
      acc[i].x += __shfl_xor(acc[i].x, m);
      acc[i].y += __shfl_xor(acc[i].y, m);
      acc[i].z += __shfl_xor(acc[i].z, m);
      acc[i].w += __shfl_xor(acc[i].w, m);
    }
    inv_l[i] = 1.0f / lsum[i];
  }
  if (l == 0) {
#pragma unroll
    for (int i = 0; i < TI; i++)
      inv_ws[((size_t)(h * BATCH + b)) * LSEQ + i0 + i] = inv_l[i];
  }
  if (jg == 0) {
#pragma unroll
    for (int i = 0; i < TI; i++) {
      float4 e = acc[i];
      e.x *= inv_l[i]; e.y *= inv_l[i]; e.z *= inv_l[i]; e.w *= inv_l[i];
      *(float4*)&embv[i * DMODEL + h * DKV + dg * 4] = e;
    }
  }
  __syncthreads();

  // FC + bias + residual: wave w owns channels [w*32, w*32+32)
  int kk = l & 15, cg = l >> 4;
#pragma unroll
  for (int p4 = 0; p4 < 8; p4++) {
    int chn = w * 32 + p4 * 4 + cg;
    float4 wv[4];
#pragma unroll
    for (int cc = 0; cc < 4; cc++)
      wv[cc] = *(const float4*)(fc_w + (size_t)chn * DMODEL + (cc * 16 + kk) * 4);
    float po[TI];
#pragma unroll
    for (int i = 0; i < TI; i++) {
      float s = 0.f;
#pragma unroll
      for (int cc = 0; cc < 4; cc++) {
        float4 e = *(const float4*)&embv[i * DMODEL + (cc * 16 + kk) * 4];
        s += wv[cc].x * e.x + wv[cc].y * e.y + wv[cc].z * e.z + wv[cc].w * e.w;
      }
      po[i] = s;
    }
#pragma unroll
    for (int m = 1; m < 16; m <<= 1) {
#pragma unroll
      for (int i = 0; i < TI; i++) po[i] += __shfl_xor(po[i], m);
    }
    if (kk == 0) {
      float fb = fc_b[chn];
#pragma unroll
      for (int i = 0; i < TI; i++) {
        size_t rr = ((size_t)(b * LSEQ + i0 + i)) * DMODEL + chn;
        out[rr] = po[i] + fb + hin[rr];
      }
    }
  }
}

// ---------------- Kernel C: attn rescale by 1/l ----------------
__global__ __launch_bounds__(256) void rescale_kernel(float* __restrict__ attn,
                                                      const float* __restrict__ inv_ws) {
  int row = blockIdx.x;  // 16384 rows
  float inv = inv_ws[row];
  float4* p = (float4*)(attn + (size_t)row * LSEQ) + threadIdx.x;
  float4 v = *p;
  v.x *= inv; v.y *= inv; v.z *= inv; v.w *= inv;
  *p = v;
}

extern "C" void kernel_launch(void* const* d_in, const int* in_sizes, int n_in,
                              void* d_out, int out_size, void* d_ws, size_t ws_size,
                              hipStream_t stream) {
  const float* h = (const float*)d_in[0];
  const float* bias = (const float*)d_in[1];
  const float* w_qs = (const float*)d_in[2];
  const float* w_ks = (const float*)d_in[3];
  const float* w_vs = (const float*)d_in[4];
  const float* ln_g = (const float*)d_in[5];
  const float* ln_b = (const float*)d_in[6];
  const float* fc_w = (const float*)d_in[7];
  const float* fc_b = (const float*)d_in[8];
  float* out = (float*)d_out;
  float* attn_out = out + (size_t)BATCH * LSEQ * DMODEL;

  float* ws = (float*)d_ws;
  float* q_ws = ws;
  float* kt_ws = q_ws + (size_t)BATCH * LSEQ * DMODEL;
  float* vt_ws = kt_ws + (size_t)BATCH * LSEQ * DMODEL;
  float* inv_ws = vt_ws + (size_t)BATCH * LSEQ * DMODEL;

  qkv_gemm_kernel<<<dim3(16, 12), 256, 0, stream>>>(h, ln_g, ln_b, w_qs, w_ks, w_vs,
                                                    q_ws, kt_ws, vt_ws);
  attn_kernel<<<BATCH * LSEQ / TI, 512, 0, stream>>>(q_ws, kt_ws, vt_ws, bias, h, fc_w,
                                                     fc_b, out, attn_out, inv_ws);
  rescale_kernel<<<NHEAD * BATCH * LSEQ, 256, 0, stream>>>(attn_out, inv_ws);
}